// Round 13
// baseline (461.546 us; speedup 1.0000x reference)
//
#include <hip/hip_runtime.h>
#include <hip/hip_bf16.h>

typedef __bf16 bf16;
typedef __bf16 bf16x8 __attribute__((ext_vector_type(8)));
typedef __bf16 bf16x4 __attribute__((ext_vector_type(4)));
typedef float  f32x4  __attribute__((ext_vector_type(4)));

#define NL 128
#define NN 10000
#define NE 160000
#define LN_EPS 1e-5f

__device__ __forceinline__ f32x4 f4zero() {
    f32x4 v; v[0] = 0.f; v[1] = 0.f; v[2] = 0.f; v[3] = 0.f; return v;
}

// LDS tiles are [row][128] bf16 (256B row stride); byte offset within a row is
// XOR-swizzled by ((row&7)<<4) (T2) to kill the stride-256B ds_read_b128 conflict.
__device__ __forceinline__ int swz_off(int row, int b) {
    return row * 256 + (b ^ ((row & 7) << 4));
}

__device__ __forceinline__ bf16x8 frag_ld(const bf16* base, int row, int kbyte) {
    return *reinterpret_cast<const bf16x8*>(
        reinterpret_cast<const char*>(base) + swz_off(row, kbyte));
}

// Copy a pre-swizzled 32 KB bf16 weight image global -> LDS (NT threads, 16B/lane).
template <int NT>
__device__ __forceinline__ void stage_img(const bf16* __restrict__ img, bf16* dst, int tid) {
    #pragma unroll
    for (int i = 0; i < 2048 / NT; ++i) {
        int byte = (i * NT + tid) * 16;
        *reinterpret_cast<bf16x8*>(reinterpret_cast<char*>(dst) + byte) =
            *reinterpret_cast<const bf16x8*>(reinterpret_cast<const char*>(img) + byte);
    }
}

// Stage 16 rows x 128 f32 -> bf16 LDS rows [wrow0 .. wrow0+15], one wave.
__device__ __forceinline__ void stage_rows16(const float* __restrict__ src0, bf16* sX,
                                             int wrow0, int lane) {
    int c8 = (lane & 15) * 8;
    #pragma unroll
    for (int i = 0; i < 4; ++i) {
        int sub = i * 4 + (lane >> 4);
        const float* src = src0 + (size_t)sub * 128 + c8;
        f32x4 a = *reinterpret_cast<const f32x4*>(src);
        f32x4 b = *reinterpret_cast<const f32x4*>(src + 4);
        bf16x8 v;
        v[0] = (bf16)a[0]; v[1] = (bf16)a[1]; v[2] = (bf16)a[2]; v[3] = (bf16)a[3];
        v[4] = (bf16)b[0]; v[5] = (bf16)b[1]; v[6] = (bf16)b[2]; v[7] = (bf16)b[3];
        *reinterpret_cast<bf16x8*>(reinterpret_cast<char*>(sX) + swz_off(wrow0 + sub, c8 * 2)) = v;
    }
}

// One wave: 16 rows x 128 cols, K=128. B from swizzled LDS image.
__device__ __forceinline__ void mfma_16x128(const bf16* sA, const bf16* sB, int arow, int kq,
                                            f32x4 acc[8]) {
    #pragma unroll
    for (int kk = 0; kk < 4; ++kk) {
        bf16x8 af = frag_ld(sA, arow, kk * 64 + kq);
        #pragma unroll
        for (int t = 0; t < 8; ++t) {
            bf16x8 bfr = frag_ld(sB, t * 16 + (arow & 15), kk * 64 + kq);
            acc[t] = __builtin_amdgcn_mfma_f32_16x16x32_bf16(af, bfr, acc[t], 0, 0, 0);
        }
    }
}

// One wave: 16 rows x 128 cols, K=128. A from wave-private LDS; B from a
// fragment-ordered GLOBAL image (L2-hot, fully coalesced 1KB/read). Layout
// verified by R11 (passing absmax).
__device__ __forceinline__ void mfma_16x128g(const bf16* sA, const bf16* __restrict__ imgB,
                                             int arow, int kq, int lane, f32x4 acc[8]) {
    #pragma unroll
    for (int kk = 0; kk < 4; ++kk) {
        bf16x8 af = frag_ld(sA, arow, kk * 64 + kq);
        #pragma unroll
        for (int t = 0; t < 8; ++t) {
            bf16x8 bfr = *reinterpret_cast<const bf16x8*>(
                imgB + (size_t)(((kk * 8 + t) * 64 + lane)) * 8);
            acc[t] = __builtin_amdgcn_mfma_f32_16x16x32_bf16(af, bfr, acc[t], 0, 0, 0);
        }
    }
}

// Write a wave's C fragments (bf16) into its private sX rows.
__device__ __forceinline__ void acc_to_lds_bf16(bf16* sX, const f32x4 acc[8], int w, int lane) {
    int c0 = lane & 15;
    #pragma unroll
    for (int r = 0; r < 4; ++r) {
        int rl = w * 16 + (lane >> 4) * 4 + r;
        #pragma unroll
        for (int t = 0; t < 8; ++t) {
            int col = t * 16 + c0;
            *reinterpret_cast<bf16*>(reinterpret_cast<char*>(sX) + swz_off(rl, col * 2)) =
                (bf16)acc[t][r];
        }
    }
}

// Coalesced copy of a wave's 16 LDS rows -> global bf16.
__device__ __forceinline__ void lds_rows_to_global_bf16(const bf16* sX, bf16* __restrict__ dst0,
                                                        int w, int lane) {
    int c8 = (lane & 15) * 8;
    #pragma unroll
    for (int i = 0; i < 4; ++i) {
        int sub = i * 4 + (lane >> 4);
        bf16x8 v = *reinterpret_cast<const bf16x8*>(
            reinterpret_cast<const char*>(sX) + swz_off(w * 16 + sub, c8 * 2));
        *reinterpret_cast<bf16x8*>(dst0 + (size_t)sub * 128 + c8) = v;
    }
}

// ---------------- weight image prep + init fused ----------------
// blocks 0..23: LDS-layout images (k_node/embed); 24..29: FRAG-layout edge W0/W1
// (k_edge); 30: glob init + done; 31: deg/agg zero.
__global__ void k_prep(const float* __restrict__ eW0, const float* __restrict__ eW1,
                       const float* __restrict__ nW0, const float* __restrict__ nW1,
                       bf16* __restrict__ imgs, bf16* __restrict__ fimgs,
                       const float* __restrict__ globals_,
                       const float* __restrict__ embW, const float* __restrict__ embB,
                       float* __restrict__ g, const float* __restrict__ eb0,
                       const float* __restrict__ nb0, float* __restrict__ gve,
                       float* __restrict__ gvn, int* __restrict__ deg,
                       float* __restrict__ eagg, float* __restrict__ nagg,
                       int* __restrict__ done) {
    const int b = blockIdx.x;
    const int tid = threadIdx.x;
    if (b < 24) {
        const int s = b >> 3, kind = b & 7;
        const float* src;
        if (kind < 3)       src = eW0 + (size_t)s * 512 * 128 + (size_t)kind * 128 * 128;
        else if (kind == 3) src = eW1 + (size_t)s * 128 * 128;
        else if (kind < 7)  src = nW0 + (size_t)s * 512 * 128 + (size_t)(kind - 4) * 128 * 128;
        else                src = nW1 + (size_t)s * 128 * 128;
        bf16* img = imgs + (size_t)b * 16384;
        for (int i = 0; i < 16; ++i) {
            int q = tid + i * 256;
            int col = q & 127;
            int k0 = (q >> 7) << 2;
            bf16x4 v;
            v[0] = (bf16)src[(k0 + 0) * 128 + col];
            v[1] = (bf16)src[(k0 + 1) * 128 + col];
            v[2] = (bf16)src[(k0 + 2) * 128 + col];
            v[3] = (bf16)src[(k0 + 3) * 128 + col];
            *reinterpret_cast<bf16x4*>(reinterpret_cast<char*>(img) + swz_off(col, k0 * 2)) = v;
        }
    } else if (b < 30) {
        // frag-layout edge weights: f = b-24; s = f>>1; which = f&1 (0:W0a, 1:W1)
        const int f = b - 24, s = f >> 1, which = f & 1;
        const float* src = which ? (eW1 + (size_t)s * 128 * 128)
                                 : (eW0 + (size_t)s * 512 * 128);
        bf16* img = fimgs + (size_t)f * 16384;
        #pragma unroll
        for (int i = 0; i < 8; ++i) {
            int q = tid + i * 256;  // 0..2047
            int l = q & 63;
            int ft = q >> 6;        // 0..31
            int kk = ft >> 3, t = ft & 7;
            int col = t * 16 + (l & 15);
            int k0 = kk * 32 + (l >> 4) * 8;
            bf16x8 v;
            #pragma unroll
            for (int j = 0; j < 8; ++j) v[j] = (bf16)src[(size_t)(k0 + j) * 128 + col];
            *reinterpret_cast<bf16x8*>(img + (size_t)q * 8) = v;
        }
    } else if (b == 30) {
        __shared__ float sG[128];
        if (tid < 3) done[tid] = 0;
        if (tid < 128) {
            float a = embB[tid];
            #pragma unroll
            for (int k = 0; k < 8; ++k) a += globals_[k] * embW[k * 128 + tid];
            g[tid] = a;
            sG[tid] = a;
        }
        __syncthreads();
        if (tid < 128) {
            const float* eW0g = eW0 + 384 * 128;
            const float* nW0g = nW0 + 384 * 128;
            float ae = eb0[tid], an = nb0[tid];
            for (int k = 0; k < 128; ++k) {
                float gv = sG[k];
                ae += gv * eW0g[k * 128 + tid];
                an += gv * nW0g[k * 128 + tid];
            }
            gve[tid] = ae;
            gvn[tid] = an;
        }
    } else {
        for (int i = tid; i < 2 * NN; i += 256) deg[i] = 0;
        for (int i = tid; i < 8 * 128; i += 256) eagg[i] = 0.f;
        for (int i = tid; i < 4 * 128; i += 256) nagg[i] = 0.f;
    }
}

// ---------------- CSR build ----------------

__global__ void k_hist(const int* __restrict__ senders, const int* __restrict__ receivers,
                       int* __restrict__ deg_s, int* __restrict__ deg_r) {
    int i = blockIdx.x * 256 + threadIdx.x;
    if (i < NE) {
        atomicAdd(&deg_s[senders[i]], 1);
        atomicAdd(&deg_r[receivers[i]], 1);
    }
}

__device__ void scan_arr(const int* __restrict__ deg, int* __restrict__ rs, int* __restrict__ cur,
                         int* sW, int* sRun) {
    const int tid = threadIdx.x, lane = tid & 63, wid = tid >> 6;
    if (tid == 0) *sRun = 0;
    __syncthreads();
    for (int base = 0; base < NN; base += 1024) {
        int i = base + tid;
        int orig = (i < NN) ? deg[i] : 0;
        int v = orig;
        #pragma unroll
        for (int off = 1; off < 64; off <<= 1) {
            int u = __shfl_up(v, off, 64);
            if (lane >= off) v += u;
        }
        if (lane == 63) sW[wid] = v;
        __syncthreads();
        if (wid == 0 && lane < 16) {
            int u = sW[lane];
            #pragma unroll
            for (int off = 1; off < 16; off <<= 1) {
                int t = __shfl_up(u, off, 16);
                if (lane >= off) u += t;
            }
            sW[lane] = u;
        }
        __syncthreads();
        int waveoff = (wid == 0) ? 0 : sW[wid - 1];
        int incl = v + waveoff + *sRun;
        if (i < NN) {
            rs[i + 1] = incl;
            cur[i] = incl - orig;
        }
        __syncthreads();
        if (tid == 1023) *sRun = incl;
        __syncthreads();
    }
    if (tid == 0) rs[0] = 0;
}

__global__ void k_scan(const int* __restrict__ deg_s, int* __restrict__ rs_s,
                       int* __restrict__ cur_s, const int* __restrict__ deg_r,
                       int* __restrict__ rs_r, int* __restrict__ cur_r) {
    __shared__ int sW[16];
    __shared__ int sRun;
    scan_arr(deg_s, rs_s, cur_s, sW, &sRun);
    __syncthreads();
    scan_arr(deg_r, rs_r, cur_r, sW, &sRun);
}

__global__ void k_scatter_s(const int* __restrict__ senders, const int* __restrict__ receivers,
                            int* __restrict__ cur_s, int* __restrict__ perm,
                            int* __restrict__ snd_s, int* __restrict__ rcv_s) {
    int i = blockIdx.x * 256 + threadIdx.x;
    if (i < NE) {
        int s = senders[i];
        int p = atomicAdd(&cur_s[s], 1);
        perm[p] = i;
        snd_s[p] = s;
        rcv_s[p] = receivers[i];
    }
}

__global__ void k_scatter_r(const int* __restrict__ rcv_s, int* __restrict__ cur_r,
                            int* __restrict__ csr_r) {
    int j = blockIdx.x * 256 + threadIdx.x;
    if (j < NE) {
        int r = rcv_s[j];
        int p = atomicAdd(&cur_r[r], 1);
        csr_r[p] = j;
    }
}

// ---------------- embed ----------------

// Node embed + FUSED step-0 projections. Row-group form: 16 lanes/row, each lane
// owns 8 contiguous cols -> vector LDS reads + 32B f32 / 16B bf16 stores.
__global__ __launch_bounds__(256, 2) void k_embed_nodes(
    const float* __restrict__ nodes, const float* __restrict__ W, const float* __restrict__ b,
    float* __restrict__ n_out, const bf16* __restrict__ imgPs, const bf16* __restrict__ imgPr,
    bf16* __restrict__ nsW, bf16* __restrict__ nrW) {
    __shared__ __align__(16) char smem[81920];
    float* sWemb = (float*)smem;            // 32KB f32 (embed phase)
    float* sB = (float*)(smem + 32768);     // 512B (embed phase)
    bf16* sWa = (bf16*)smem;                // proj phase
    bf16* sWb = (bf16*)(smem + 32768);
    bf16* sX = (bf16*)(smem + 65536);       // 16KB
    const int tid = threadIdx.x;
    const int lane = tid & 63;
    const int w = tid >> 6;
    const int rowbase = blockIdx.x * 64;
    const bool wvalid = (rowbase + w * 16) < NN;

    for (int i = tid; i < 64 * 128; i += 256) sWemb[i] = W[i];
    if (tid < 128) sB[tid] = b[tid];
    __syncthreads();

    const int rg = tid >> 4;        // 0..15: row within pass
    const int c8 = (tid & 15) * 8;  // 8 contiguous output cols
    #pragma unroll
    for (int p = 0; p < 4; ++p) {
        int row = rowbase + p * 16 + rg;
        if (row < NN) {
            const f32x4* x4 = reinterpret_cast<const f32x4*>(nodes + (size_t)row * 64);
            float o[8];
            #pragma unroll
            for (int j = 0; j < 8; ++j) o[j] = sB[c8 + j];
            #pragma unroll
            for (int k4 = 0; k4 < 16; ++k4) {
                f32x4 xv = x4[k4];
                #pragma unroll
                for (int kk = 0; kk < 4; ++kk) {
                    float x = xv[kk];
                    const float* wrow = sWemb + (k4 * 4 + kk) * 128 + c8;
                    f32x4 wA = *reinterpret_cast<const f32x4*>(wrow);
                    f32x4 wB = *reinterpret_cast<const f32x4*>(wrow + 4);
                    o[0] += x * wA[0]; o[1] += x * wA[1]; o[2] += x * wA[2]; o[3] += x * wA[3];
                    o[4] += x * wB[0]; o[5] += x * wB[1]; o[6] += x * wB[2]; o[7] += x * wB[3];
                }
            }
            f32x4 oA, oB;
            bf16x8 v;
            #pragma unroll
            for (int j = 0; j < 8; ++j) {
                if (j < 4) oA[j] = o[j]; else oB[j - 4] = o[j];
                v[j] = (bf16)o[j];
            }
            float* orow = n_out + (size_t)row * 128 + c8;
            *reinterpret_cast<f32x4*>(orow) = oA;
            *reinterpret_cast<f32x4*>(orow + 4) = oB;
            *reinterpret_cast<bf16x8*>(reinterpret_cast<char*>(sX) +
                                       swz_off(p * 16 + rg, c8 * 2)) = v;
        }
    }
    __syncthreads();  // embed done with sWemb/sB; sX holds n (bf16)
    stage_img<256>(imgPs, sWa, tid);
    stage_img<256>(imgPr, sWb, tid);
    __syncthreads();
    if (!wvalid) return;

    const int arow = w * 16 + (lane & 15);
    const int kq = (lane >> 4) * 16;
    f32x4 acc[8], acc2[8];
    #pragma unroll
    for (int t = 0; t < 8; ++t) { acc[t] = f4zero(); acc2[t] = f4zero(); }
    mfma_16x128(sX, sWa, arow, kq, acc);
    mfma_16x128(sX, sWb, arow, kq, acc2);

    acc_to_lds_bf16(sX, acc, w, lane);
    lds_rows_to_global_bf16(sX, nsW + (size_t)(rowbase + w * 16) * 128, w, lane);
    acc_to_lds_bf16(sX, acc2, w, lane);
    lds_rows_to_global_bf16(sX, nrW + (size_t)(rowbase + w * 16) * 128, w, lane);
}

// Embeds edges[perm[j]] -> e[j] (bf16). Row-group form.
__global__ __launch_bounds__(256) void k_embed_edges(const float* __restrict__ edges,
                                                     const int* __restrict__ perm,
                                                     const float* __restrict__ W,
                                                     const float* __restrict__ b,
                                                     bf16* __restrict__ e_out) {
    __shared__ float sW[16 * 128];
    __shared__ float sB[128];
    const int tid = threadIdx.x;
    for (int i = tid; i < 16 * 128; i += 256) sW[i] = W[i];
    if (tid < 128) sB[tid] = b[tid];
    __syncthreads();
    const int rg = tid >> 4;
    const int c8 = (tid & 15) * 8;
    const int rowbase = blockIdx.x * 128;
    #pragma unroll 2
    for (int p = 0; p < 8; ++p) {
        int row = rowbase + p * 16 + rg;
        int src = perm[row];
        const f32x4* x4 = reinterpret_cast<const f32x4*>(edges + (size_t)src * 16);
        f32x4 xr[4] = {x4[0], x4[1], x4[2], x4[3]};
        float o[8];
        #pragma unroll
        for (int j = 0; j < 8; ++j) o[j] = sB[c8 + j];
        #pragma unroll
        for (int q = 0; q < 4; ++q) {
            #pragma unroll
            for (int kk = 0; kk < 4; ++kk) {
                float x = xr[q][kk];
                const float* wrow = sW + (q * 4 + kk) * 128 + c8;
                f32x4 wA = *reinterpret_cast<const f32x4*>(wrow);
                f32x4 wB = *reinterpret_cast<const f32x4*>(wrow + 4);
                o[0] += x * wA[0]; o[1] += x * wA[1]; o[2] += x * wA[2]; o[3] += x * wA[3];
                o[4] += x * wB[0]; o[5] += x * wB[1]; o[6] += x * wB[2]; o[7] += x * wB[3];
            }
        }
        bf16x8 v;
        #pragma unroll
        for (int j = 0; j < 8; ++j) v[j] = (bf16)o[j];
        *reinterpret_cast<bf16x8*>(e_out + (size_t)row * 128 + c8) = v;
    }
}

// ---------------- per-step kernels ----------------

// Edge update, BARRIER-FREE weights: 256 threads / 64 rows; W0/W1 read as
// fragment-ordered global images (L2-hot, coalesced 1KB/MFMA-step); only LDS is
// wave-private sX (16KB) + eagg scratch -> 18KB, ~4 blocks/CU independent gangs.
// Aggregation unchanged (gather-based k_agg; NO scatter atomics -- R1/R11 lesson).
__global__ __launch_bounds__(256) void k_edge(
    bf16* e_rw, bf16* __restrict__ e_new_out, const bf16* __restrict__ nsW,
    const bf16* __restrict__ nrW, float* __restrict__ edge_agg,
    const int* __restrict__ snd_s, const int* __restrict__ rcv_s,
    const bf16* __restrict__ fimgW0, const bf16* __restrict__ fimgW1,
    const float* __restrict__ gvec, const float* __restrict__ b1,
    const float* __restrict__ lnS, const float* __restrict__ lnO) {
    __shared__ __align__(16) char smem[18432];
    bf16* sX = (bf16*)smem;                  // 4 waves * 16 rows * 256B = 16KB
    float* sEagg = (float*)(smem + 16384);   // 4*128 floats

    const int tid = threadIdx.x;
    const int lane = tid & 63;
    const int w = tid >> 6;  // 0..3
    const int rowbase = blockIdx.x * 64;
    const int arow = w * 16 + (lane & 15);
    const int kq = (lane >> 4) * 16;
    const int c0 = lane & 15;
    const int qrt = lane >> 4;
    const int c8 = c0 * 8;

    // indices + e rows
    int snd_i[4], rcv_i[4];
    bf16x8 eold8[4];
    #pragma unroll
    for (int i = 0; i < 4; ++i) {
        int gr = rowbase + w * 16 + i * 4 + qrt;
        snd_i[i] = snd_s[gr];
        rcv_i[i] = rcv_s[gr];
        eold8[i] = *reinterpret_cast<const bf16x8*>(e_rw + (size_t)gr * 128 + c8);
    }
    // gathers issued early (T14)
    bf16x8 ns8[4], nr8[4];
    #pragma unroll
    for (int i = 0; i < 4; ++i) {
        ns8[i] = *reinterpret_cast<const bf16x8*>(nsW + (size_t)snd_i[i] * 128 + c8);
        nr8[i] = *reinterpret_cast<const bf16x8*>(nrW + (size_t)rcv_i[i] * 128 + c8);
    }
    f32x4 gvA = *reinterpret_cast<const f32x4*>(gvec + c8);
    f32x4 gvB = *reinterpret_cast<const f32x4*>(gvec + c8 + 4);

    // wave-private e rows -> sX (same-wave producer/consumer: no barrier)
    #pragma unroll
    for (int i = 0; i < 4; ++i)
        *reinterpret_cast<bf16x8*>(reinterpret_cast<char*>(sX) +
                                   swz_off(w * 16 + i * 4 + qrt, c8 * 2)) = eold8[i];

    // layer 0 (B from global frag image)
    f32x4 acc[8];
    #pragma unroll
    for (int t = 0; t < 8; ++t) acc[t] = f4zero();
    __builtin_amdgcn_s_setprio(1);
    mfma_16x128g(sX, fimgW0, arow, kq, lane, acc);
    __builtin_amdgcn_s_setprio(0);

    // fragment -> LDS transpose (wave-private rows)
    #pragma unroll
    for (int r = 0; r < 4; ++r) {
        int rl = w * 16 + qrt * 4 + r;
        #pragma unroll
        for (int t = 0; t < 8; ++t)
            *reinterpret_cast<bf16*>(reinterpret_cast<char*>(sX) +
                                     swz_off(rl, (t * 16 + c0) * 2)) = (bf16)acc[t][r];
    }
    // row-space fixup: h = relu(a + nsW[snd] + nrW[rcv] + gvec)
    #pragma unroll
    for (int i = 0; i < 4; ++i) {
        int rl = w * 16 + i * 4 + qrt;
        bf16x8 a8 = *reinterpret_cast<const bf16x8*>(
            reinterpret_cast<const char*>(sX) + swz_off(rl, c8 * 2));
        bf16x8 h8;
        #pragma unroll
        for (int j = 0; j < 8; ++j) {
            float gvj = (j < 4) ? gvA[j] : gvB[j - 4];
            float v = (float)a8[j] + (float)ns8[i][j] + (float)nr8[i][j] + gvj;
            h8[j] = (bf16)fmaxf(v, 0.f);
        }
        *reinterpret_cast<bf16x8*>(reinterpret_cast<char*>(sX) + swz_off(rl, c8 * 2)) = h8;
    }

    // layer 1 (B from global frag image)
    f32x4 acc2[8];
    #pragma unroll
    for (int t = 0; t < 8; ++t) acc2[t] = f4zero();
    __builtin_amdgcn_s_setprio(1);
    mfma_16x128g(sX, fimgW1, arow, kq, lane, acc2);
    __builtin_amdgcn_s_setprio(0);

    float bb[8];
    #pragma unroll
    for (int t = 0; t < 8; ++t) bb[t] = b1[t * 16 + c0];
    f32x4 lsA = *reinterpret_cast<const f32x4*>(lnS + c8);
    f32x4 lsB = *reinterpret_cast<const f32x4*>(lnS + c8 + 4);
    f32x4 loA = *reinterpret_cast<const f32x4*>(lnO + c8);
    f32x4 loB = *reinterpret_cast<const f32x4*>(lnO + c8 + 4);

    // fragment -> LDS transpose with +b1, relu (this IS e_new in bf16)
    #pragma unroll
    for (int r = 0; r < 4; ++r) {
        int rl = w * 16 + qrt * 4 + r;
        #pragma unroll
        for (int t = 0; t < 8; ++t)
            *reinterpret_cast<bf16*>(reinterpret_cast<char*>(sX) +
                                     swz_off(rl, (t * 16 + c0) * 2)) =
                (bf16)fmaxf(acc2[t][r] + bb[t], 0.f);
    }

    // row-space epilogue: e_new store, colsum, residual + LN, e store
    float cs[8];
    #pragma unroll
    for (int j = 0; j < 8; ++j) cs[j] = 0.f;
    bf16* enew0 = e_new_out + (size_t)rowbase * 128;
    bf16* e0 = e_rw + (size_t)rowbase * 128;
    #pragma unroll
    for (int i = 0; i < 4; ++i) {
        int sub = w * 16 + i * 4 + qrt;
        bf16x8 en8 = *reinterpret_cast<const bf16x8*>(
            reinterpret_cast<const char*>(sX) + swz_off(sub, c8 * 2));
        *reinterpret_cast<bf16x8*>(enew0 + (size_t)sub * 128 + c8) = en8;
        float rv[8], s1 = 0.f, s2 = 0.f;
        #pragma unroll
        for (int j = 0; j < 8; ++j) {
            float en = (float)en8[j];
            cs[j] += en;
            float v = en + (float)eold8[i][j];
            rv[j] = v;
            s1 += v;
            s2 += v * v;
        }
        #pragma unroll
        for (int off = 1; off < 16; off <<= 1) {
            s1 += __shfl_xor(s1, off, 16);
            s2 += __shfl_xor(s2, off, 16);
        }
        float mean = s1 * (1.f / 128.f);
        float rstd = rsqrtf(s2 * (1.f / 128.f) - mean * mean + LN_EPS);
        bf16x8 o8;
        #pragma unroll
        for (int j = 0; j < 8; ++j) {
            float ls = (j < 4) ? lsA[j] : lsB[j - 4];
            float lo = (j < 4) ? loA[j] : loB[j - 4];
            o8[j] = (bf16)((rv[j] - mean) * rstd * ls + lo);
        }
        *reinterpret_cast<bf16x8*>(e0 + (size_t)sub * 128 + c8) = o8;
    }

    // edge_agg block reduction (only barriers in the kernel)
    #pragma unroll
    for (int j = 0; j < 8; ++j) {
        cs[j] += __shfl_xor(cs[j], 16, 64);
        cs[j] += __shfl_xor(cs[j], 32, 64);
    }
    __syncthreads();
    if (qrt == 0) {
        float* dst = sEagg + w * 128 + c8;
        #pragma unroll
        for (int j = 0; j < 8; ++j) dst[j] = cs[j];
    }
    __syncthreads();
    if (tid < 128) {
        float v = sEagg[tid] + sEagg[128 + tid] + sEagg[256 + tid] + sEagg[384 + tid];
        atomicAdd(&edge_agg[(blockIdx.x & 7) * 128 + tid], v);
    }
}

// Standalone two-sided aggregation: one node per wave (10k waves of TLP),
// qrt-strided 4-deep over the segment -> 16 loads in flight per wave. bf16 out.
__global__ __launch_bounds__(256) void k_agg(const bf16* __restrict__ e_new,
                                             const int* __restrict__ rs_s,
                                             const int* __restrict__ rs_r,
                                             const int* __restrict__ csr_r,
                                             bf16* __restrict__ sent, bf16* __restrict__ recv) {
    const int lane = threadIdx.x & 63;
    const int w = threadIdx.x >> 6;
    const int node = blockIdx.x * 4 + w;
    if (node >= NN) return;
    const int qrt = lane >> 4;
    const int c8 = (lane & 15) * 8;
    float a[8];
    #pragma unroll
    for (int j = 0; j < 8; ++j) a[j] = 0.f;
    const int b0 = rs_s[node], b1 = rs_s[node + 1];
    for (int jj = b0 + qrt; jj < b1; jj += 4) {
        bf16x8 v = *reinterpret_cast<const bf16x8*>(e_new + (size_t)jj * 128 + c8);
        #pragma unroll
        for (int j = 0; j < 8; ++j) a[j] += (float)v[j];
    }
    #pragma unroll
    for (int j = 0; j < 8; ++j) {
        a[j] += __shfl_xor(a[j], 16, 64);
        a[j] += __shfl_xor(a[j], 32, 64);
    }
    if (qrt == 0) {
        bf16x8 o;
        #pragma unroll
        for (int j = 0; j < 8; ++j) o[j] = (bf16)a[j];
        *reinterpret_cast<bf16x8*>(sent + (size_t)node * 128 + c8) = o;
    }
    #pragma unroll
    for (int j = 0; j < 8; ++j) a[j] = 0.f;
    const int c1 = rs_r[node], c2 = rs_r[node + 1];
    for (int pp = c1 + qrt; pp < c2; pp += 4) {
        int jj = csr_r[pp];
        bf16x8 v = *reinterpret_cast<const bf16x8*>(e_new + (size_t)jj * 128 + c8);
        #pragma unroll
        for (int j = 0; j < 8; ++j) a[j] += (float)v[j];
    }
    #pragma unroll
    for (int j = 0; j < 8; ++j) {
        a[j] += __shfl_xor(a[j], 16, 64);
        a[j] += __shfl_xor(a[j], 32, 64);
    }
    if (qrt == 0) {
        bf16x8 o;
        #pragma unroll
        for (int j = 0; j < 8; ++j) o[j] = (bf16)a[j];
        *reinterpret_cast<bf16x8*>(recv + (size_t)node * 128 + c8) = o;
    }
}

// Slim node update: sent/recv arrive precomputed (bf16); A/B weight rotation;
// fused next-step proj; nagg; LAST-BLOCK GLOBAL UPDATE.
__global__ __launch_bounds__(256, 2) void k_node(
    float* n_rw, const bf16* __restrict__ sent, const bf16* __restrict__ recv,
    float* __restrict__ node_agg /*4x128*/, const bf16* __restrict__ imgW0,
    const bf16* __restrict__ imgW1, const float* __restrict__ gvec,
    const float* __restrict__ b1, const float* __restrict__ lnS,
    const float* __restrict__ lnO, const bf16* __restrict__ imgPs,
    const bf16* __restrict__ imgPr, bf16* __restrict__ nsW, bf16* __restrict__ nrW,
    int do_proj,
    // glob-tail params
    int* __restrict__ done_ctr, float* __restrict__ edge_agg /*8x128*/, float* __restrict__ g,
    const float* __restrict__ gW0, const float* __restrict__ gb0,
    const float* __restrict__ gW1, const float* __restrict__ gb1,
    const float* __restrict__ glnS, const float* __restrict__ glnO,
    const float* __restrict__ eW0g, const float* __restrict__ eb0n,
    const float* __restrict__ nW0g, const float* __restrict__ nb0n,
    float* __restrict__ gve, float* __restrict__ gvn, const float* __restrict__ decW,
    const float* __restrict__ decb, float* __restrict__ out, int do_next, int do_dec) {
    __shared__ __align__(16) char smem[81920];
    __shared__ int sLast;
    bf16* sA = (bf16*)smem;
    bf16* sB = (bf16*)(smem + 32768);
    bf16* sX = (bf16*)(smem + 65536);
    float* sNagg = (float*)smem;  // alias; used after final barrier

    const int tid = threadIdx.x;
    const int lane = tid & 63;
    const int w = tid >> 6;
    const int rowbase = blockIdx.x * 64;
    const bool wvalid = (rowbase + w * 16) < NN;
    const int arow = w * 16 + (lane & 15);
    const int kq = (lane >> 4) * 16;
    const int c0 = lane & 15;
    const int qrt = lane >> 4;
    const int c8 = c0 * 8;

    stage_img<256>(imgW0, sA, tid);           // W0a
    stage_img<256>(imgW0 + 16384, sB, tid);   // W0b
    bf16x8 sent8[4], recv8[4];
    if (wvalid) {
        stage_rows16(n_rw + (size_t)(rowbase + w * 16) * 128, sX, w * 16, lane);
        #pragma unroll
        for (int i = 0; i < 4; ++i) {
            int gr = rowbase + w * 16 + i * 4 + qrt;
            sent8[i] = *reinterpret_cast<const bf16x8*>(sent + (size_t)gr * 128 + c8);
            recv8[i] = *reinterpret_cast<const bf16x8*>(recv + (size_t)gr * 128 + c8);
        }
    }
    __syncthreads();  // (1)

    float gvf[8], bbf[8];
    #pragma unroll
    for (int t = 0; t < 8; ++t) {
        gvf[t] = gvec[t * 16 + c0];
        bbf[t] = b1[t * 16 + c0];
    }
    f32x4 lsA4 = *reinterpret_cast<const f32x4*>(lnS + c8);
    f32x4 lsB4 = *reinterpret_cast<const f32x4*>(lnS + c8 + 4);
    f32x4 loA4 = *reinterpret_cast<const f32x4*>(lnO + c8);
    f32x4 loB4 = *reinterpret_cast<const f32x4*>(lnO + c8 + 4);

    f32x4 acc[8];
    #pragma unroll
    for (int t = 0; t < 8; ++t) acc[t] = f4zero();
    float cs[8];
    #pragma unroll
    for (int j = 0; j < 8; ++j) cs[j] = 0.f;

    if (wvalid) mfma_16x128(sX, sA, arow, kq, acc);  // n @ W0a
    __syncthreads();  // (2)

    stage_img<256>(imgW0 + 32768, sA, tid);  // A <- W0c
    if (wvalid) {
        #pragma unroll
        for (int i = 0; i < 4; ++i)
            *reinterpret_cast<bf16x8*>(reinterpret_cast<char*>(sX) +
                                       swz_off(w * 16 + i * 4 + qrt, c8 * 2)) = sent8[i];
        mfma_16x128(sX, sB, arow, kq, acc);  // sent @ W0b
    }
    __syncthreads();  // (3)

    stage_img<256>(imgW1, sB, tid);  // B <- W1
    if (wvalid) {
        #pragma unroll
        for (int i = 0; i < 4; ++i)
            *reinterpret_cast<bf16x8*>(reinterpret_cast<char*>(sX) +
                                       swz_off(w * 16 + i * 4 + qrt, c8 * 2)) = recv8[i];
        mfma_16x128(sX, sA, arow, kq, acc);  // recv @ W0c

        #pragma unroll
        for (int r = 0; r < 4; ++r) {
            int rl = w * 16 + (lane >> 4) * 4 + r;
            #pragma unroll
            for (int t = 0; t < 8; ++t)
                *reinterpret_cast<bf16*>(reinterpret_cast<char*>(sX) +
                                         swz_off(rl, (t * 16 + c0) * 2)) =
                    (bf16)fmaxf(acc[t][r] + gvf[t], 0.f);
        }
    }
    __syncthreads();  // (4)

    if (wvalid) {
        #pragma unroll
        for (int t = 0; t < 8; ++t) acc[t] = f4zero();
        mfma_16x128(sX, sB, arow, kq, acc);
        #pragma unroll
        for (int r = 0; r < 4; ++r) {
            int rl = w * 16 + (lane >> 4) * 4 + r;
            #pragma unroll
            for (int t = 0; t < 8; ++t)
                *reinterpret_cast<bf16*>(reinterpret_cast<char*>(sX) +
                                         swz_off(rl, (t * 16 + c0) * 2)) =
                    (bf16)fmaxf(acc[t][r] + bbf[t], 0.f);
        }

        const float* nbase = n_rw + (size_t)(rowbase + w * 16) * 128;
        #pragma unroll
        for (int i = 0; i < 4; ++i) {
            int sub = i * 4 + qrt;
            bf16x8 en8 = *reinterpret_cast<const bf16x8*>(
                reinterpret_cast<const char*>(sX) + swz_off(w * 16 + sub, c8 * 2));
            f32x4 noA = *reinterpret_cast<const f32x4*>(nbase + (size_t)sub * 128 + c8);
            f32x4 noB = *reinterpret_cast<const f32x4*>(nbase + (size_t)sub * 128 + c8 + 4);
            float rv[8], s1 = 0.f, s2 = 0.f;
            #pragma unroll
            for (int j = 0; j < 8; ++j) {
                float en = (float)en8[j];
                cs[j] += en;
                float v = en + ((j < 4) ? noA[j] : noB[j - 4]);
                rv[j] = v;
                s1 += v;
                s2 += v * v;
            }
            #pragma unroll
            for (int off = 1; off < 16; off <<= 1) {
                s1 += __shfl_xor(s1, off, 16);
                s2 += __shfl_xor(s2, off, 16);
            }
            float mean = s1 * (1.f / 128.f);
            float rstd = rsqrtf(s2 * (1.f / 128.f) - mean * mean + LN_EPS);
            f32x4 oA, oB;
            bf16x8 l8;
            #pragma unroll
            for (int j = 0; j < 8; ++j) {
                float ls = (j < 4) ? lsA4[j] : lsB4[j - 4];
                float lo = (j < 4) ? loA4[j] : loB4[j - 4];
                float o = (rv[j] - mean) * rstd * ls + lo;
                if (j < 4) oA[j] = o; else oB[j - 4] = o;
                l8[j] = (bf16)o;
            }
            float* orow = n_rw + (size_t)(rowbase + w * 16 + sub) * 128 + c8;
            *reinterpret_cast<f32x4*>(orow) = oA;
            *reinterpret_cast<f32x4*>(orow + 4) = oB;
            *reinterpret_cast<bf16x8*>(reinterpret_cast<char*>(sX) +
                                       swz_off(w * 16 + sub, c8 * 2)) = l8;
        }
    }

    if (do_proj) {
        __syncthreads();  // (5)
        stage_img<256>(imgPs, sA, tid);
        stage_img<256>(imgPr, sB, tid);
        __syncthreads();  // (6)
        if (wvalid) {
            f32x4 pa[8], pb[8];
            #pragma unroll
            for (int t = 0; t < 8; ++t) { pa[t] = f4zero(); pb[t] = f4zero(); }
            mfma_16x128(sX, sA, arow, kq, pa);
            mfma_16x128(sX, sB, arow, kq, pb);
            acc_to_lds_bf16(sX, pa, w, lane);
            lds_rows_to_global_bf16(sX, nsW + (size_t)(rowbase + w * 16) * 128, w, lane);
            acc_to_lds_bf16(sX, pb, w, lane);
            lds_rows_to_global_bf16(sX, nrW + (size_t)(rowbase + w * 16) * 128, w, lane);
        }
    }

    // node_agg reduction into one of 4 copies
    #pragma unroll
    for (int j = 0; j < 8; ++j) {
        cs[j] += __shfl_xor(cs[j], 16, 64);
        cs[j] += __shfl_xor(cs[j], 32, 64);
    }
    __syncthreads();  // (7)
    if (qrt == 0) {
        float* dst = sNagg + w * 128 + c8;
        #pragma unroll
        for (int j = 0; j < 8; ++j) dst[j] = wvalid ? cs[j] : 0.f;
    }
    __syncthreads();
    if (tid < 128) {
        float v = sNagg[tid] + sNagg[128 + tid] + sNagg[256 + tid] + sNagg[384 + tid];
        atomicAdd(&node_agg[(blockIdx.x & 3) * 128 + tid], v);
    }

    // ---- last-block global update ----
    __syncthreads();
    if (tid == 0) {
        __threadfence();
        int old = atomicAdd(done_ctr, 1);
        sLast = (old == (int)gridDim.x - 1);
    }
    __syncthreads();
    if (!sLast) return;

    float* sIn = (float*)smem;        // 384
    float* sP0 = sIn + 384;           // 128
    float* sP1 = sP0 + 128;           // 128
    float* sH = sP1 + 128;            // 128
    float* sG = sH + 128;             // 128
    float* sMR = sG + 128;            // 2
    const int j = tid & 127;
    const int part = tid >> 7;  // 0/1

    if (tid < 128) {
        float v = 0.f;
        #pragma unroll
        for (int c = 0; c < 4; ++c) v += atomicAdd(&node_agg[c * 128 + tid], 0.f);
        #pragma unroll
        for (int c = 0; c < 4; ++c) atomicExch(&node_agg[c * 128 + tid], 0.f);
        sIn[tid] = v;
        sIn[256 + tid] = g[tid];  // previous dispatch's write: coherent
    } else {
        float v = 0.f;
        #pragma unroll
        for (int c = 0; c < 8; ++c) v += edge_agg[c * 128 + j];  // prev dispatch
        #pragma unroll
        for (int c = 0; c < 8; ++c) edge_agg[c * 128 + j] = 0.f;
        sIn[128 + j] = v;
    }
    __syncthreads();
    {
        float p = 0.f;
        for (int k = 0; k < 192; ++k) {
            int kk = part * 192 + k;
            p += sIn[kk] * gW0[(size_t)kk * 128 + j];
        }
        (part ? sP1 : sP0)[j] = p;
    }
    __syncthreads();
    if (tid < 128) sH[tid] = fmaxf(gb0[tid] + sP0[tid] + sP1[tid], 0.f);
    __syncthreads();
    {
        float p = 0.f;
        for (int k = 0; k < 64; ++k) {
            int kk = part * 64 + k;
            p += sH[kk] * gW1[(size_t)kk * 128 + j];
        }
        (part ? sP1 : sP0)[j] = p;
    }
    __syncthreads();
    float res = 0.f;
    if (tid < 128) {
        res = fmaxf(gb1[tid] + sP0[tid] + sP1[tid], 0.f) + sIn[256 + tid];
        sP0[tid] = res;
        sP1[tid] = res * res;
    }
    __syncthreads();
    if (tid < 64) {
        float a = sP0[tid] + sP0[tid + 64];
        float q = sP1[tid] + sP1[tid + 64];
        #pragma unroll
        for (int off = 1; off < 64; off <<= 1) {
            a += __shfl_xor(a, off, 64);
            q += __shfl_xor(q, off, 64);
        }
        if (tid == 0) {
            float m = a * (1.f / 128.f);
            float v = q * (1.f / 128.f) - m * m;
            sMR[0] = m;
            sMR[1] = rsqrtf(v + LN_EPS);
        }
    }
    __syncthreads();
    if (tid < 128) {
        float go = (res - sMR[0]) * sMR[1] * glnS[tid] + glnO[tid];
        g[tid] = go;
        sG[tid] = go;
    }
    __syncthreads();
    if (do_next) {
        float pe = 0.f, pn = 0.f;
        for (int k = 0; k < 64; ++k) {
            int kk = part * 64 + k;
            float gv = sG[kk];
            pe += gv * eW0g[(size_t)kk * 128 + j];
            pn += gv * nW0g[(size_t)kk * 128 + j];
        }
        (part ? sP1 : sP0)[j] = pe;
        sIn[part * 128 + j] = pn;
        __syncthreads();
        if (tid < 128) {
            gve[tid] = eb0n[tid] + sP0[tid] + sP1[tid];
            gvn[tid] = nb0n[tid] + sIn[tid] + sIn[128 + tid];
        }
    }
    if (do_dec && tid < 8) {
        float a = decb[tid];
        for (int k = 0; k < 128; ++k) a += sG[k] * decW[k * 8 + tid];
        out[tid] = a;
    }
}

extern "C" void kernel_launch(void* const* d_in, const int* in_sizes, int n_in, void* d_out,
                              int out_size, void* d_ws, size_t ws_size, hipStream_t stream) {
    (void)in_sizes; (void)n_in; (void)out_size; (void)ws_size;
    const float* nodes = (const float*)d_in[0];
    const float* edges = (const float*)d_in[1];
    const float* globals_ = (const float*)d_in[2];
    const int* senders = (const int*)d_in[3];
    const int* receivers = (const int*)d_in[4];
    const float* emb_node_W = (const float*)d_in[5];
    const float* emb_node_b = (const float*)d_in[6];
    const float* emb_edge_W = (const float*)d_in[7];
    const float* emb_edge_b = (const float*)d_in[8];
    const float* emb_glob_W = (const float*)d_in[9];
    const float* emb_glob_b = (const float*)d_in[10];
    const float* edge_W0 = (const float*)d_in[11];
    const float* edge_b0 = (const float*)d_in[12];
    const float* edge_W1 = (const float*)d_in[13];
    const float* edge_b1 = (const float*)d_in[14];
    const float* node_W0 = (const float*)d_in[15];
    const float* node_b0 = (const float*)d_in[16];
    const float* node_W1 = (const float*)d_in[17];
    const float* node_b1 = (const float*)d_in[18];
    const float* glob_W0 = (const float*)d_in[19];
    const float* glob_b0 = (const float*)d_in[20];
    const float* glob_W1 = (const float*)d_in[21];
    const float* glob_b1 = (const float*)d_in[22];
    const float* ln_scale = (const float*)d_in[23];
    const float* ln_offset = (const float*)d_in[24];
    const float* dec_W = (const float*)d_in[25];
    const float* dec_b = (const float*)d_in[26];

    char* ws = (char*)d_ws;
    size_t off = 0;
    auto alloc = [&](size_t bytes) -> char* {
        char* p = ws + off;
        off += (bytes + 255) & ~(size_t)255;
        return p;
    };
    bf16* e = (bf16*)alloc((size_t)NE * NL * 2);
    bf16* e_new = (bf16*)alloc((size_t)NE * NL * 2);
    float* n = (float*)alloc((size_t)NN * NL * 4);
    bf16* nsW = (bf16*)alloc((size_t)NN * NL * 2);
    bf16* nrW = (bf16*)alloc((size_t)NN * NL * 2);
    bf16* sent = (bf16*)alloc((size_t)NN * NL * 2);
    bf16* recv = (bf16*)alloc((size_t)NN * NL * 2);
    bf16* imgs = (bf16*)alloc((size_t)24 * 16384 * 2);
    bf16* fimgs = (bf16*)alloc((size_t)6 * 16384 * 2);
    float* eagg = (float*)alloc(8 * 128 * 4);
    float* nagg = (float*)alloc(4 * 128 * 4);
    float* g = (float*)alloc(128 * 4);
    float* gve = (float*)alloc(128 * 4);
    float* gvn = (float*)alloc(128 * 4);
    int* done = (int*)alloc(16 * 4);
    int* deg = (int*)alloc((size_t)2 * NN * 4);  // deg_s | deg_r contiguous
    int* deg_s = deg;
    int* deg_r = deg + NN;
    int* rs_s = (int*)alloc((size_t)(NN + 1) * 4);
    int* rs_r = (int*)alloc((size_t)(NN + 1) * 4);
    int* cur_s = (int*)alloc((size_t)NN * 4);
    int* cur_r = (int*)alloc((size_t)NN * 4);
    int* perm = (int*)alloc((size_t)NE * 4);
    int* snd_s = (int*)alloc((size_t)NE * 4);
    int* rcv_s = (int*)alloc((size_t)NE * 4);
    int* csr_r = (int*)alloc((size_t)NE * 4);

    const int NB_N = (NN + 63) / 64;     // 157
    const int NB_E = NE / 64;            // 2500
    const int NB_EMB = NE / 128;         // 1250
    const int NB_SC = (NE + 255) / 256;  // 625
    const int NB_AGG = NN / 4;           // 2500

    auto img = [&](int s, int kind) -> const bf16* {
        return imgs + ((size_t)s * 8 + kind) * 16384;
    };
    auto fimg = [&](int s, int which) -> const bf16* {
        return fimgs + ((size_t)s * 2 + which) * 16384;
    };

    k_prep<<<32, 256, 0, stream>>>(edge_W0, edge_W1, node_W0, node_W1, imgs, fimgs, globals_,
                                   emb_glob_W, emb_glob_b, g, edge_b0, node_b0, gve, gvn,
                                   deg, eagg, nagg, done);

    k_hist<<<NB_SC, 256, 0, stream>>>(senders, receivers, deg_s, deg_r);
    k_scan<<<1, 1024, 0, stream>>>(deg_s, rs_s, cur_s, deg_r, rs_r, cur_r);
    k_scatter_s<<<NB_SC, 256, 0, stream>>>(senders, receivers, cur_s, perm, snd_s, rcv_s);
    k_scatter_r<<<NB_SC, 256, 0, stream>>>(rcv_s, cur_r, csr_r);

    k_embed_nodes<<<NB_N, 256, 0, stream>>>(nodes, emb_node_W, emb_node_b, n, img(0, 1),
                                            img(0, 2), nsW, nrW);
    k_embed_edges<<<NB_EMB, 256, 0, stream>>>(edges, perm, emb_edge_W, emb_edge_b, e);

    for (int s = 0; s < 3; ++s) {
        const int last = (s == 2);
        k_edge<<<NB_E, 256, 0, stream>>>(e, e_new, nsW, nrW, eagg, snd_s, rcv_s, fimg(s, 0),
                                         fimg(s, 1), gve, edge_b1 + s * 128,
                                         ln_scale + (s * 3 + 1) * 128,
                                         ln_offset + (s * 3 + 1) * 128);
        k_agg<<<NB_AGG, 256, 0, stream>>>(e_new, rs_s, rs_r, csr_r, sent, recv);
        const float* eW0g = last ? edge_W0 : edge_W0 + (size_t)(s + 1) * 512 * 128 + 384 * 128;
        const float* eb0n = last ? edge_b0 : edge_b0 + (s + 1) * 128;
        const float* nW0g = last ? node_W0 : node_W0 + (size_t)(s + 1) * 512 * 128 + 384 * 128;
        const float* nb0n = last ? node_b0 : node_b0 + (s + 1) * 128;
        k_node<<<NB_N, 256, 0, stream>>>(
            n, sent, recv, nagg, img(s, 4), img(s, 7), gvn, node_b1 + s * 128,
            ln_scale + (s * 3 + 0) * 128, ln_offset + (s * 3 + 0) * 128,
            img(last ? 0 : s + 1, 1), img(last ? 0 : s + 1, 2), nsW, nrW, !last,
            done + s, eagg, g, glob_W0 + (size_t)s * 384 * 128, glob_b0 + s * 128,
            glob_W1 + (size_t)s * 128 * 128, glob_b1 + s * 128, ln_scale + (s * 3 + 2) * 128,
            ln_offset + (s * 3 + 2) * 128, eW0g, eb0n, nW0g, nb0n, gve, gvn, dec_W, dec_b,
            (float*)d_out, !last, last);
    }
}

// Round 14
// 400.002 us; speedup vs baseline: 1.1539x; 1.1539x over previous
//
#include <hip/hip_runtime.h>
#include <hip/hip_bf16.h>

typedef __bf16 bf16;
typedef __bf16 bf16x8 __attribute__((ext_vector_type(8)));
typedef __bf16 bf16x4 __attribute__((ext_vector_type(4)));
typedef float  f32x4  __attribute__((ext_vector_type(4)));

#define NL 128
#define NN 10000
#define NE 160000
#define LN_EPS 1e-5f

__device__ __forceinline__ f32x4 f4zero() {
    f32x4 v; v[0] = 0.f; v[1] = 0.f; v[2] = 0.f; v[3] = 0.f; return v;
}

// LDS tiles are [row][128] bf16 (256B row stride); byte offset within a row is
// XOR-swizzled by ((row&7)<<4) (T2) to kill the stride-256B ds_read_b128 conflict.
__device__ __forceinline__ int swz_off(int row, int b) {
    return row * 256 + (b ^ ((row & 7) << 4));
}

__device__ __forceinline__ bf16x8 frag_ld(const bf16* base, int row, int kbyte) {
    return *reinterpret_cast<const bf16x8*>(
        reinterpret_cast<const char*>(base) + swz_off(row, kbyte));
}

// Copy a pre-swizzled 32 KB bf16 weight image global -> LDS (NT threads, 16B/lane).
template <int NT>
__device__ __forceinline__ void stage_img(const bf16* __restrict__ img, bf16* dst, int tid) {
    #pragma unroll
    for (int i = 0; i < 2048 / NT; ++i) {
        int byte = (i * NT + tid) * 16;
        *reinterpret_cast<bf16x8*>(reinterpret_cast<char*>(dst) + byte) =
            *reinterpret_cast<const bf16x8*>(reinterpret_cast<const char*>(img) + byte);
    }
}

// T14 split staging: issue loads early, write LDS later (transient regs only;
// NEVER held across an MFMA -- R4/R6 spill lesson).
template <int NT>
__device__ __forceinline__ void stage_img_ld(const bf16* __restrict__ img, bf16x8* r, int tid) {
    #pragma unroll
    for (int i = 0; i < 2048 / NT; ++i)
        r[i] = *reinterpret_cast<const bf16x8*>(reinterpret_cast<const char*>(img) +
                                                (i * NT + tid) * 16);
}
template <int NT>
__device__ __forceinline__ void stage_img_st(bf16* dst, const bf16x8* r, int tid) {
    #pragma unroll
    for (int i = 0; i < 2048 / NT; ++i)
        *reinterpret_cast<bf16x8*>(reinterpret_cast<char*>(dst) + (i * NT + tid) * 16) = r[i];
}

// Stage 16 rows x 128 f32 -> bf16 LDS rows [wrow0 .. wrow0+15], one wave.
__device__ __forceinline__ void stage_rows16(const float* __restrict__ src0, bf16* sX,
                                             int wrow0, int lane) {
    int c8 = (lane & 15) * 8;
    #pragma unroll
    for (int i = 0; i < 4; ++i) {
        int sub = i * 4 + (lane >> 4);
        const float* src = src0 + (size_t)sub * 128 + c8;
        f32x4 a = *reinterpret_cast<const f32x4*>(src);
        f32x4 b = *reinterpret_cast<const f32x4*>(src + 4);
        bf16x8 v;
        v[0] = (bf16)a[0]; v[1] = (bf16)a[1]; v[2] = (bf16)a[2]; v[3] = (bf16)a[3];
        v[4] = (bf16)b[0]; v[5] = (bf16)b[1]; v[6] = (bf16)b[2]; v[7] = (bf16)b[3];
        *reinterpret_cast<bf16x8*>(reinterpret_cast<char*>(sX) + swz_off(wrow0 + sub, c8 * 2)) = v;
    }
}

// One wave: 16 rows x 128 cols, K=128.
__device__ __forceinline__ void mfma_16x128(const bf16* sA, const bf16* sB, int arow, int kq,
                                            f32x4 acc[8]) {
    #pragma unroll
    for (int kk = 0; kk < 4; ++kk) {
        bf16x8 af = frag_ld(sA, arow, kk * 64 + kq);
        #pragma unroll
        for (int t = 0; t < 8; ++t) {
            bf16x8 bfr = frag_ld(sB, t * 16 + (arow & 15), kk * 64 + kq);
            acc[t] = __builtin_amdgcn_mfma_f32_16x16x32_bf16(af, bfr, acc[t], 0, 0, 0);
        }
    }
}

// Write a wave's C fragments (bf16) into its private sX rows.
__device__ __forceinline__ void acc_to_lds_bf16(bf16* sX, const f32x4 acc[8], int w, int lane) {
    int c0 = lane & 15;
    #pragma unroll
    for (int r = 0; r < 4; ++r) {
        int rl = w * 16 + (lane >> 4) * 4 + r;
        #pragma unroll
        for (int t = 0; t < 8; ++t) {
            int col = t * 16 + c0;
            *reinterpret_cast<bf16*>(reinterpret_cast<char*>(sX) + swz_off(rl, col * 2)) =
                (bf16)acc[t][r];
        }
    }
}

// Coalesced copy of a wave's 16 LDS rows -> global bf16.
__device__ __forceinline__ void lds_rows_to_global_bf16(const bf16* sX, bf16* __restrict__ dst0,
                                                        int w, int lane) {
    int c8 = (lane & 15) * 8;
    #pragma unroll
    for (int i = 0; i < 4; ++i) {
        int sub = i * 4 + (lane >> 4);
        bf16x8 v = *reinterpret_cast<const bf16x8*>(
            reinterpret_cast<const char*>(sX) + swz_off(w * 16 + sub, c8 * 2));
        *reinterpret_cast<bf16x8*>(dst0 + (size_t)sub * 128 + c8) = v;
    }
}

// ---------------- weight image prep + init fused ----------------
__global__ void k_prep(const float* __restrict__ eW0, const float* __restrict__ eW1,
                       const float* __restrict__ nW0, const float* __restrict__ nW1,
                       bf16* __restrict__ imgs, const float* __restrict__ globals_,
                       const float* __restrict__ embW, const float* __restrict__ embB,
                       float* __restrict__ g, const float* __restrict__ eb0,
                       const float* __restrict__ nb0, float* __restrict__ gve,
                       float* __restrict__ gvn, int* __restrict__ deg,
                       float* __restrict__ eagg, float* __restrict__ nagg,
                       int* __restrict__ done) {
    const int b = blockIdx.x;
    const int tid = threadIdx.x;
    if (b < 24) {
        const int s = b >> 3, kind = b & 7;
        const float* src;
        if (kind < 3)       src = eW0 + (size_t)s * 512 * 128 + (size_t)kind * 128 * 128;
        else if (kind == 3) src = eW1 + (size_t)s * 128 * 128;
        else if (kind < 7)  src = nW0 + (size_t)s * 512 * 128 + (size_t)(kind - 4) * 128 * 128;
        else                src = nW1 + (size_t)s * 128 * 128;
        bf16* img = imgs + (size_t)b * 16384;
        for (int i = 0; i < 16; ++i) {
            int q = tid + i * 256;
            int col = q & 127;
            int k0 = (q >> 7) << 2;
            bf16x4 v;
            v[0] = (bf16)src[(k0 + 0) * 128 + col];
            v[1] = (bf16)src[(k0 + 1) * 128 + col];
            v[2] = (bf16)src[(k0 + 2) * 128 + col];
            v[3] = (bf16)src[(k0 + 3) * 128 + col];
            *reinterpret_cast<bf16x4*>(reinterpret_cast<char*>(img) + swz_off(col, k0 * 2)) = v;
        }
    } else if (b == 24) {
        __shared__ float sG[128];
        if (tid < 3) done[tid] = 0;
        if (tid < 128) {
            float a = embB[tid];
            #pragma unroll
            for (int k = 0; k < 8; ++k) a += globals_[k] * embW[k * 128 + tid];
            g[tid] = a;
            sG[tid] = a;
        }
        __syncthreads();
        if (tid < 128) {
            const float* eW0g = eW0 + 384 * 128;
            const float* nW0g = nW0 + 384 * 128;
            float ae = eb0[tid], an = nb0[tid];
            for (int k = 0; k < 128; ++k) {
                float gv = sG[k];
                ae += gv * eW0g[k * 128 + tid];
                an += gv * nW0g[k * 128 + tid];
            }
            gve[tid] = ae;
            gvn[tid] = an;
        }
    } else {
        for (int i = tid; i < 2 * NN; i += 256) deg[i] = 0;
        for (int i = tid; i < 8 * 128; i += 256) eagg[i] = 0.f;
        for (int i = tid; i < 4 * 128; i += 256) nagg[i] = 0.f;
    }
}

// ---------------- CSR build ----------------

__global__ void k_hist(const int* __restrict__ senders, const int* __restrict__ receivers,
                       int* __restrict__ deg_s, int* __restrict__ deg_r) {
    int i = blockIdx.x * 256 + threadIdx.x;
    if (i < NE) {
        atomicAdd(&deg_s[senders[i]], 1);
        atomicAdd(&deg_r[receivers[i]], 1);
    }
}

__device__ void scan_arr(const int* __restrict__ deg, int* __restrict__ rs, int* __restrict__ cur,
                         int* sW, int* sRun) {
    const int tid = threadIdx.x, lane = tid & 63, wid = tid >> 6;
    if (tid == 0) *sRun = 0;
    __syncthreads();
    for (int base = 0; base < NN; base += 1024) {
        int i = base + tid;
        int orig = (i < NN) ? deg[i] : 0;
        int v = orig;
        #pragma unroll
        for (int off = 1; off < 64; off <<= 1) {
            int u = __shfl_up(v, off, 64);
            if (lane >= off) v += u;
        }
        if (lane == 63) sW[wid] = v;
        __syncthreads();
        if (wid == 0 && lane < 16) {
            int u = sW[lane];
            #pragma unroll
            for (int off = 1; off < 16; off <<= 1) {
                int t = __shfl_up(u, off, 16);
                if (lane >= off) u += t;
            }
            sW[lane] = u;
        }
        __syncthreads();
        int waveoff = (wid == 0) ? 0 : sW[wid - 1];
        int incl = v + waveoff + *sRun;
        if (i < NN) {
            rs[i + 1] = incl;
            cur[i] = incl - orig;
        }
        __syncthreads();
        if (tid == 1023) *sRun = incl;
        __syncthreads();
    }
    if (tid == 0) rs[0] = 0;
}

__global__ void k_scan(const int* __restrict__ deg_s, int* __restrict__ rs_s,
                       int* __restrict__ cur_s, const int* __restrict__ deg_r,
                       int* __restrict__ rs_r, int* __restrict__ cur_r) {
    __shared__ int sW[16];
    __shared__ int sRun;
    scan_arr(deg_s, rs_s, cur_s, sW, &sRun);
    __syncthreads();
    scan_arr(deg_r, rs_r, cur_r, sW, &sRun);
}

__global__ void k_scatter_s(const int* __restrict__ senders, const int* __restrict__ receivers,
                            int* __restrict__ cur_s, int* __restrict__ perm,
                            int* __restrict__ snd_s, int* __restrict__ rcv_s) {
    int i = blockIdx.x * 256 + threadIdx.x;
    if (i < NE) {
        int s = senders[i];
        int p = atomicAdd(&cur_s[s], 1);
        perm[p] = i;
        snd_s[p] = s;
        rcv_s[p] = receivers[i];
    }
}

__global__ void k_scatter_r(const int* __restrict__ rcv_s, int* __restrict__ cur_r,
                            int* __restrict__ csr_r) {
    int j = blockIdx.x * 256 + threadIdx.x;
    if (j < NE) {
        int r = rcv_s[j];
        int p = atomicAdd(&cur_r[r], 1);
        csr_r[p] = j;
    }
}

// ---------------- embed ----------------

// Node embed + FUSED step-0 projections. Row-group form: 16 lanes/row, each lane
// owns 8 contiguous cols -> vector LDS reads + 32B f32 / 16B bf16 stores.
__global__ __launch_bounds__(256, 2) void k_embed_nodes(
    const float* __restrict__ nodes, const float* __restrict__ W, const float* __restrict__ b,
    float* __restrict__ n_out, const bf16* __restrict__ imgPs, const bf16* __restrict__ imgPr,
    bf16* __restrict__ nsW, bf16* __restrict__ nrW) {
    __shared__ __align__(16) char smem[81920];
    float* sWemb = (float*)smem;            // 32KB f32 (embed phase)
    float* sB = (float*)(smem + 32768);     // 512B (embed phase)
    bf16* sWa = (bf16*)smem;                // proj phase
    bf16* sWb = (bf16*)(smem + 32768);
    bf16* sX = (bf16*)(smem + 65536);       // 16KB
    const int tid = threadIdx.x;
    const int lane = tid & 63;
    const int w = tid >> 6;
    const int rowbase = blockIdx.x * 64;
    const bool wvalid = (rowbase + w * 16) < NN;

    for (int i = tid; i < 64 * 128; i += 256) sWemb[i] = W[i];
    if (tid < 128) sB[tid] = b[tid];
    __syncthreads();

    const int rg = tid >> 4;        // 0..15: row within pass
    const int c8 = (tid & 15) * 8;  // 8 contiguous output cols
    #pragma unroll
    for (int p = 0; p < 4; ++p) {
        int row = rowbase + p * 16 + rg;
        if (row < NN) {
            const f32x4* x4 = reinterpret_cast<const f32x4*>(nodes + (size_t)row * 64);
            float o[8];
            #pragma unroll
            for (int j = 0; j < 8; ++j) o[j] = sB[c8 + j];
            #pragma unroll
            for (int k4 = 0; k4 < 16; ++k4) {
                f32x4 xv = x4[k4];
                #pragma unroll
                for (int kk = 0; kk < 4; ++kk) {
                    float x = xv[kk];
                    const float* wrow = sWemb + (k4 * 4 + kk) * 128 + c8;
                    f32x4 wA = *reinterpret_cast<const f32x4*>(wrow);
                    f32x4 wB = *reinterpret_cast<const f32x4*>(wrow + 4);
                    o[0] += x * wA[0]; o[1] += x * wA[1]; o[2] += x * wA[2]; o[3] += x * wA[3];
                    o[4] += x * wB[0]; o[5] += x * wB[1]; o[6] += x * wB[2]; o[7] += x * wB[3];
                }
            }
            f32x4 oA, oB;
            bf16x8 v;
            #pragma unroll
            for (int j = 0; j < 8; ++j) {
                if (j < 4) oA[j] = o[j]; else oB[j - 4] = o[j];
                v[j] = (bf16)o[j];
            }
            float* orow = n_out + (size_t)row * 128 + c8;
            *reinterpret_cast<f32x4*>(orow) = oA;
            *reinterpret_cast<f32x4*>(orow + 4) = oB;
            *reinterpret_cast<bf16x8*>(reinterpret_cast<char*>(sX) +
                                       swz_off(p * 16 + rg, c8 * 2)) = v;
        }
    }
    __syncthreads();  // embed done with sWemb/sB; sX holds n (bf16)
    stage_img<256>(imgPs, sWa, tid);
    stage_img<256>(imgPr, sWb, tid);
    __syncthreads();
    if (!wvalid) return;

    const int arow = w * 16 + (lane & 15);
    const int kq = (lane >> 4) * 16;
    f32x4 acc[8], acc2[8];
    #pragma unroll
    for (int t = 0; t < 8; ++t) { acc[t] = f4zero(); acc2[t] = f4zero(); }
    mfma_16x128(sX, sWa, arow, kq, acc);
    mfma_16x128(sX, sWb, arow, kq, acc2);

    acc_to_lds_bf16(sX, acc, w, lane);
    lds_rows_to_global_bf16(sX, nsW + (size_t)(rowbase + w * 16) * 128, w, lane);
    acc_to_lds_bf16(sX, acc2, w, lane);
    lds_rows_to_global_bf16(sX, nrW + (size_t)(rowbase + w * 16) * 128, w, lane);
}

// Embeds edges[perm[j]] -> e[j] (bf16). Row-group form: 16 lanes/row, 8 cols/lane,
// bf16x8 stores; 8 independent row-passes keep multiple gathers in flight.
__global__ __launch_bounds__(256) void k_embed_edges(const float* __restrict__ edges,
                                                     const int* __restrict__ perm,
                                                     const float* __restrict__ W,
                                                     const float* __restrict__ b,
                                                     bf16* __restrict__ e_out) {
    __shared__ float sW[16 * 128];
    __shared__ float sB[128];
    const int tid = threadIdx.x;
    for (int i = tid; i < 16 * 128; i += 256) sW[i] = W[i];
    if (tid < 128) sB[tid] = b[tid];
    __syncthreads();
    const int rg = tid >> 4;
    const int c8 = (tid & 15) * 8;
    const int rowbase = blockIdx.x * 128;
    #pragma unroll 2
    for (int p = 0; p < 8; ++p) {
        int row = rowbase + p * 16 + rg;
        int src = perm[row];
        const f32x4* x4 = reinterpret_cast<const f32x4*>(edges + (size_t)src * 16);
        f32x4 xr[4] = {x4[0], x4[1], x4[2], x4[3]};
        float o[8];
        #pragma unroll
        for (int j = 0; j < 8; ++j) o[j] = sB[c8 + j];
        #pragma unroll
        for (int q = 0; q < 4; ++q) {
            #pragma unroll
            for (int kk = 0; kk < 4; ++kk) {
                float x = xr[q][kk];
                const float* wrow = sW + (q * 4 + kk) * 128 + c8;
                f32x4 wA = *reinterpret_cast<const f32x4*>(wrow);
                f32x4 wB = *reinterpret_cast<const f32x4*>(wrow + 4);
                o[0] += x * wA[0]; o[1] += x * wA[1]; o[2] += x * wA[2]; o[3] += x * wA[3];
                o[4] += x * wB[0]; o[5] += x * wB[1]; o[6] += x * wB[2]; o[7] += x * wB[3];
            }
        }
        bf16x8 v;
        #pragma unroll
        for (int j = 0; j < 8; ++j) v[j] = (bf16)o[j];
        *reinterpret_cast<bf16x8*>(e_out + (size_t)row * 128 + c8) = v;
    }
}

// ---------------- per-step kernels ----------------

// Edge update, 512-thread / 128-row blocks; 64 KB LDS (2 blocks/CU).
__global__ __launch_bounds__(512, 2) void k_edge(
    bf16* e_rw, bf16* __restrict__ e_new_out, const bf16* __restrict__ nsW,
    const bf16* __restrict__ nrW, float* __restrict__ edge_agg,
    const int* __restrict__ snd_s, const int* __restrict__ rcv_s,
    const bf16* __restrict__ imgW0, const bf16* __restrict__ imgW1,
    const float* __restrict__ gvec, const float* __restrict__ b1,
    const float* __restrict__ lnS, const float* __restrict__ lnO) {
    __shared__ __align__(16) char smem[65536];
    bf16* sW = (bf16*)smem;
    bf16* sX = (bf16*)(smem + 32768);
    float* sEagg = (float*)smem;

    const int tid = threadIdx.x;
    const int lane = tid & 63;
    const int w = tid >> 6;
    const int rowbase = blockIdx.x * 128;
    const int arow = w * 16 + (lane & 15);
    const int kq = (lane >> 4) * 16;
    const int c0 = lane & 15;
    const int qrt = lane >> 4;
    const int c8 = c0 * 8;

    stage_img<512>(imgW0, sW, tid);

    int snd_i[4], rcv_i[4];
    bf16x8 eold8[4];
    #pragma unroll
    for (int i = 0; i < 4; ++i) {
        int gr = rowbase + w * 16 + i * 4 + qrt;
        snd_i[i] = snd_s[gr];
        rcv_i[i] = rcv_s[gr];
        eold8[i] = *reinterpret_cast<const bf16x8*>(e_rw + (size_t)gr * 128 + c8);
    }

    f32x4 gvA = *reinterpret_cast<const f32x4*>(gvec + c8);
    f32x4 gvB = *reinterpret_cast<const f32x4*>(gvec + c8 + 4);
    f32x4 lsA = *reinterpret_cast<const f32x4*>(lnS + c8);
    f32x4 lsB = *reinterpret_cast<const f32x4*>(lnS + c8 + 4);
    f32x4 loA = *reinterpret_cast<const f32x4*>(lnO + c8);
    f32x4 loB = *reinterpret_cast<const f32x4*>(lnO + c8 + 4);
    float bb[8];
    #pragma unroll
    for (int t = 0; t < 8; ++t) bb[t] = b1[t * 16 + c0];

    bf16x8 ns8[4], nr8[4];
    #pragma unroll
    for (int i = 0; i < 4; ++i) {
        ns8[i] = *reinterpret_cast<const bf16x8*>(nsW + (size_t)snd_i[i] * 128 + c8);
        nr8[i] = *reinterpret_cast<const bf16x8*>(nrW + (size_t)rcv_i[i] * 128 + c8);
    }

    #pragma unroll
    for (int i = 0; i < 4; ++i)
        *reinterpret_cast<bf16x8*>(reinterpret_cast<char*>(sX) +
                                   swz_off(w * 16 + i * 4 + qrt, c8 * 2)) = eold8[i];

    __syncthreads();

    f32x4 acc[8];
    #pragma unroll
    for (int t = 0; t < 8; ++t) acc[t] = f4zero();
    __builtin_amdgcn_s_setprio(1);
    mfma_16x128(sX, sW, arow, kq, acc);
    __builtin_amdgcn_s_setprio(0);

    __syncthreads();

    bf16x8 w1r[4];
    stage_img_ld<512>(imgW1, w1r, tid);

    #pragma unroll
    for (int r = 0; r < 4; ++r) {
        int rl = w * 16 + (lane >> 4) * 4 + r;
        #pragma unroll
        for (int t = 0; t < 8; ++t)
            *reinterpret_cast<bf16*>(reinterpret_cast<char*>(sX) +
                                     swz_off(rl, (t * 16 + c0) * 2)) = (bf16)acc[t][r];
    }
    #pragma unroll
    for (int i = 0; i < 4; ++i) {
        int rl = w * 16 + i * 4 + qrt;
        bf16x8 a8 = *reinterpret_cast<const bf16x8*>(
            reinterpret_cast<const char*>(sX) + swz_off(rl, c8 * 2));
        bf16x8 h8;
        #pragma unroll
        for (int j = 0; j < 8; ++j) {
            float gvj = (j < 4) ? gvA[j] : gvB[j - 4];
            float v = (float)a8[j] + (float)ns8[i][j] + (float)nr8[i][j] + gvj;
            h8[j] = (bf16)fmaxf(v, 0.f);
        }
        *reinterpret_cast<bf16x8*>(reinterpret_cast<char*>(sX) + swz_off(rl, c8 * 2)) = h8;
    }

    stage_img_st<512>(sW, w1r, tid);
    __syncthreads();

    f32x4 acc2[8];
    #pragma unroll
    for (int t = 0; t < 8; ++t) acc2[t] = f4zero();
    __builtin_amdgcn_s_setprio(1);
    mfma_16x128(sX, sW, arow, kq, acc2);
    __builtin_amdgcn_s_setprio(0);

    #pragma unroll
    for (int r = 0; r < 4; ++r) {
        int rl = w * 16 + (lane >> 4) * 4 + r;
        #pragma unroll
        for (int t = 0; t < 8; ++t)
            *reinterpret_cast<bf16*>(reinterpret_cast<char*>(sX) +
                                     swz_off(rl, (t * 16 + c0) * 2)) =
                (bf16)fmaxf(acc2[t][r] + bb[t], 0.f);
    }

    float cs[8];
    #pragma unroll
    for (int j = 0; j < 8; ++j) cs[j] = 0.f;
    bf16* enew0 = e_new_out + (size_t)rowbase * 128;
    bf16* e0 = e_rw + (size_t)rowbase * 128;
    #pragma unroll
    for (int i = 0; i < 4; ++i) {
        int sub = w * 16 + i * 4 + qrt;
        bf16x8 en8 = *reinterpret_cast<const bf16x8*>(
            reinterpret_cast<const char*>(sX) + swz_off(sub, c8 * 2));
        *reinterpret_cast<bf16x8*>(enew0 + (size_t)sub * 128 + c8) = en8;
        float rv[8], s1 = 0.f, s2 = 0.f;
        #pragma unroll
        for (int j = 0; j < 8; ++j) {
            float en = (float)en8[j];
            cs[j] += en;
            float v = en + (float)eold8[i][j];
            rv[j] = v;
            s1 += v;
            s2 += v * v;
        }
        #pragma unroll
        for (int off = 1; off < 16; off <<= 1) {
            s1 += __shfl_xor(s1, off, 16);
            s2 += __shfl_xor(s2, off, 16);
        }
        float mean = s1 * (1.f / 128.f);
        float rstd = rsqrtf(s2 * (1.f / 128.f) - mean * mean + LN_EPS);
        bf16x8 o8;
        #pragma unroll
        for (int j = 0; j < 8; ++j) {
            float ls = (j < 4) ? lsA[j] : lsB[j - 4];
            float lo = (j < 4) ? loA[j] : loB[j - 4];
            o8[j] = (bf16)((rv[j] - mean) * rstd * ls + lo);
        }
        *reinterpret_cast<bf16x8*>(e0 + (size_t)sub * 128 + c8) = o8;
    }

    #pragma unroll
    for (int j = 0; j < 8; ++j) {
        cs[j] += __shfl_xor(cs[j], 16, 64);
        cs[j] += __shfl_xor(cs[j], 32, 64);
    }
    __syncthreads();
    if (qrt == 0) {
        float* dst = sEagg + w * 128 + c8;
        #pragma unroll
        for (int j = 0; j < 8; ++j) dst[j] = cs[j];
    }
    __syncthreads();
    if (tid < 128) {
        float v = 0.f;
        #pragma unroll
        for (int ww = 0; ww < 8; ++ww) v += sEagg[ww * 128 + tid];
        atomicAdd(&edge_agg[(blockIdx.x & 7) * 128 + tid], v);
    }
}

// Standalone two-sided aggregation: one node per wave (10k waves of TLP),
// qrt-strided 4-deep over the segment -> 16 loads in flight per wave. bf16 out.
__global__ __launch_bounds__(256) void k_agg(const bf16* __restrict__ e_new,
                                             const int* __restrict__ rs_s,
                                             const int* __restrict__ rs_r,
                                             const int* __restrict__ csr_r,
                                             bf16* __restrict__ sent, bf16* __restrict__ recv) {
    const int lane = threadIdx.x & 63;
    const int w = threadIdx.x >> 6;
    const int node = blockIdx.x * 4 + w;
    if (node >= NN) return;
    const int qrt = lane >> 4;
    const int c8 = (lane & 15) * 8;
    float a[8];
    #pragma unroll
    for (int j = 0; j < 8; ++j) a[j] = 0.f;
    const int b0 = rs_s[node], b1 = rs_s[node + 1];
    for (int jj = b0 + qrt; jj < b1; jj += 4) {
        bf16x8 v = *reinterpret_cast<const bf16x8*>(e_new + (size_t)jj * 128 + c8);
        #pragma unroll
        for (int j = 0; j < 8; ++j) a[j] += (float)v[j];
    }
    #pragma unroll
    for (int j = 0; j < 8; ++j) {
        a[j] += __shfl_xor(a[j], 16, 64);
        a[j] += __shfl_xor(a[j], 32, 64);
    }
    if (qrt == 0) {
        bf16x8 o;
        #pragma unroll
        for (int j = 0; j < 8; ++j) o[j] = (bf16)a[j];
        *reinterpret_cast<bf16x8*>(sent + (size_t)node * 128 + c8) = o;
    }
    #pragma unroll
    for (int j = 0; j < 8; ++j) a[j] = 0.f;
    const int c1 = rs_r[node], c2 = rs_r[node + 1];
    for (int pp = c1 + qrt; pp < c2; pp += 4) {
        int jj = csr_r[pp];
        bf16x8 v = *reinterpret_cast<const bf16x8*>(e_new + (size_t)jj * 128 + c8);
        #pragma unroll
        for (int j = 0; j < 8; ++j) a[j] += (float)v[j];
    }
    #pragma unroll
    for (int j = 0; j < 8; ++j) {
        a[j] += __shfl_xor(a[j], 16, 64);
        a[j] += __shfl_xor(a[j], 32, 64);
    }
    if (qrt == 0) {
        bf16x8 o;
        #pragma unroll
        for (int j = 0; j < 8; ++j) o[j] = (bf16)a[j];
        *reinterpret_cast<bf16x8*>(recv + (size_t)node * 128 + c8) = o;
    }
}

// Slim node update: sent/recv arrive precomputed (bf16); A/B weight rotation;
// fused next-step proj; nagg; LAST-BLOCK GLOBAL UPDATE.
__global__ __launch_bounds__(256, 2) void k_node(
    float* n_rw, const bf16* __restrict__ sent, const bf16* __restrict__ recv,
    float* __restrict__ node_agg /*4x128*/, const bf16* __restrict__ imgW0,
    const bf16* __restrict__ imgW1, const float* __restrict__ gvec,
    const float* __restrict__ b1, const float* __restrict__ lnS,
    const float* __restrict__ lnO, const bf16* __restrict__ imgPs,
    const bf16* __restrict__ imgPr, bf16* __restrict__ nsW, bf16* __restrict__ nrW,
    int do_proj,
    // glob-tail params
    int* __restrict__ done_ctr, float* __restrict__ edge_agg /*8x128*/, float* __restrict__ g,
    const float* __restrict__ gW0, const float* __restrict__ gb0,
    const float* __restrict__ gW1, const float* __restrict__ gb1,
    const float* __restrict__ glnS, const float* __restrict__ glnO,
    const float* __restrict__ eW0g, const float* __restrict__ eb0n,
    const float* __restrict__ nW0g, const float* __restrict__ nb0n,
    float* __restrict__ gve, float* __restrict__ gvn, const float* __restrict__ decW,
    const float* __restrict__ decb, float* __restrict__ out, int do_next, int do_dec) {
    __shared__ __align__(16) char smem[81920];
    __shared__ int sLast;
    bf16* sA = (bf16*)smem;
    bf16* sB = (bf16*)(smem + 32768);
    bf16* sX = (bf16*)(smem + 65536);
    float* sNagg = (float*)smem;  // alias; used after final barrier

    const int tid = threadIdx.x;
    const int lane = tid & 63;
    const int w = tid >> 6;
    const int rowbase = blockIdx.x * 64;
    const bool wvalid = (rowbase + w * 16) < NN;
    const int arow = w * 16 + (lane & 15);
    const int kq = (lane >> 4) * 16;
    const int c0 = lane & 15;
    const int qrt = lane >> 4;
    const int c8 = c0 * 8;

    stage_img<256>(imgW0, sA, tid);           // W0a
    stage_img<256>(imgW0 + 16384, sB, tid);   // W0b
    bf16x8 sent8[4], recv8[4];
    if (wvalid) {
        stage_rows16(n_rw + (size_t)(rowbase + w * 16) * 128, sX, w * 16, lane);
        #pragma unroll
        for (int i = 0; i < 4; ++i) {
            int gr = rowbase + w * 16 + i * 4 + qrt;
            sent8[i] = *reinterpret_cast<const bf16x8*>(sent + (size_t)gr * 128 + c8);
            recv8[i] = *reinterpret_cast<const bf16x8*>(recv + (size_t)gr * 128 + c8);
        }
    }
    __syncthreads();  // (1)

    float gvf[8], bbf[8];
    #pragma unroll
    for (int t = 0; t < 8; ++t) {
        gvf[t] = gvec[t * 16 + c0];
        bbf[t] = b1[t * 16 + c0];
    }
    f32x4 lsA4 = *reinterpret_cast<const f32x4*>(lnS + c8);
    f32x4 lsB4 = *reinterpret_cast<const f32x4*>(lnS + c8 + 4);
    f32x4 loA4 = *reinterpret_cast<const f32x4*>(lnO + c8);
    f32x4 loB4 = *reinterpret_cast<const f32x4*>(lnO + c8 + 4);

    f32x4 acc[8];
    #pragma unroll
    for (int t = 0; t < 8; ++t) acc[t] = f4zero();
    float cs[8];
    #pragma unroll
    for (int j = 0; j < 8; ++j) cs[j] = 0.f;

    if (wvalid) mfma_16x128(sX, sA, arow, kq, acc);  // n @ W0a
    __syncthreads();  // (2)

    stage_img<256>(imgW0 + 32768, sA, tid);  // A <- W0c
    if (wvalid) {
        #pragma unroll
        for (int i = 0; i < 4; ++i)
            *reinterpret_cast<bf16x8*>(reinterpret_cast<char*>(sX) +
                                       swz_off(w * 16 + i * 4 + qrt, c8 * 2)) = sent8[i];
        mfma_16x128(sX, sB, arow, kq, acc);  // sent @ W0b
    }
    __syncthreads();  // (3)

    stage_img<256>(imgW1, sB, tid);  // B <- W1
    if (wvalid) {
        #pragma unroll
        for (int i = 0; i < 4; ++i)
            *reinterpret_cast<bf16x8*>(reinterpret_cast<char*>(sX) +
                                       swz_off(w * 16 + i * 4 + qrt, c8 * 2)) = recv8[i];
        mfma_16x128(sX, sA, arow, kq, acc);  // recv @ W0c

        #pragma unroll
        for (int r = 0; r < 4; ++r) {
            int rl = w * 16 + (lane >> 4) * 4 + r;
            #pragma unroll
            for (int t = 0; t < 8; ++t)
                *reinterpret_cast<bf16*>(reinterpret_cast<char*>(sX) +
                                         swz_off(rl, (t * 16 + c0) * 2)) =
                    (bf16)fmaxf(acc[t][r] + gvf[t], 0.f);
        }
    }
    __syncthreads();  // (4)

    if (wvalid) {
        #pragma unroll
        for (int t = 0; t < 8; ++t) acc[t] = f4zero();
        mfma_16x128(sX, sB, arow, kq, acc);
        #pragma unroll
        for (int r = 0; r < 4; ++r) {
            int rl = w * 16 + (lane >> 4) * 4 + r;
            #pragma unroll
            for (int t = 0; t < 8; ++t)
                *reinterpret_cast<bf16*>(reinterpret_cast<char*>(sX) +
                                         swz_off(rl, (t * 16 + c0) * 2)) =
                    (bf16)fmaxf(acc[t][r] + bbf[t], 0.f);
        }

        const float* nbase = n_rw + (size_t)(rowbase + w * 16) * 128;
        #pragma unroll
        for (int i = 0; i < 4; ++i) {
            int sub = i * 4 + qrt;
            bf16x8 en8 = *reinterpret_cast<const bf16x8*>(
                reinterpret_cast<const char*>(sX) + swz_off(w * 16 + sub, c8 * 2));
            f32x4 noA = *reinterpret_cast<const f32x4*>(nbase + (size_t)sub * 128 + c8);
            f32x4 noB = *reinterpret_cast<const f32x4*>(nbase + (size_t)sub * 128 + c8 + 4);
            float rv[8], s1 = 0.f, s2 = 0.f;
            #pragma unroll
            for (int j = 0; j < 8; ++j) {
                float en = (float)en8[j];
                cs[j] += en;
                float v = en + ((j < 4) ? noA[j] : noB[j - 4]);
                rv[j] = v;
                s1 += v;
                s2 += v * v;
            }
            #pragma unroll
            for (int off = 1; off < 16; off <<= 1) {
                s1 += __shfl_xor(s1, off, 16);
                s2 += __shfl_xor(s2, off, 16);
            }
            float mean = s1 * (1.f / 128.f);
            float rstd = rsqrtf(s2 * (1.f / 128.f) - mean * mean + LN_EPS);
            f32x4 oA, oB;
            bf16x8 l8;
            #pragma unroll
            for (int j = 0; j < 8; ++j) {
                float ls = (j < 4) ? lsA4[j] : lsB4[j - 4];
                float lo = (j < 4) ? loA4[j] : loB4[j - 4];
                float o = (rv[j] - mean) * rstd * ls + lo;
                if (j < 4) oA[j] = o; else oB[j - 4] = o;
                l8[j] = (bf16)o;
            }
            float* orow = n_rw + (size_t)(rowbase + w * 16 + sub) * 128 + c8;
            *reinterpret_cast<f32x4*>(orow) = oA;
            *reinterpret_cast<f32x4*>(orow + 4) = oB;
            *reinterpret_cast<bf16x8*>(reinterpret_cast<char*>(sX) +
                                       swz_off(w * 16 + sub, c8 * 2)) = l8;
        }
    }

    if (do_proj) {
        __syncthreads();  // (5)
        stage_img<256>(imgPs, sA, tid);
        stage_img<256>(imgPr, sB, tid);
        __syncthreads();  // (6)
        if (wvalid) {
            f32x4 pa[8], pb[8];
            #pragma unroll
            for (int t = 0; t < 8; ++t) { pa[t] = f4zero(); pb[t] = f4zero(); }
            mfma_16x128(sX, sA, arow, kq, pa);
            mfma_16x128(sX, sB, arow, kq, pb);
            acc_to_lds_bf16(sX, pa, w, lane);
            lds_rows_to_global_bf16(sX, nsW + (size_t)(rowbase + w * 16) * 128, w, lane);
            acc_to_lds_bf16(sX, pb, w, lane);
            lds_rows_to_global_bf16(sX, nrW + (size_t)(rowbase + w * 16) * 128, w, lane);
        }
    }

    // node_agg reduction into one of 4 copies
    #pragma unroll
    for (int j = 0; j < 8; ++j) {
        cs[j] += __shfl_xor(cs[j], 16, 64);
        cs[j] += __shfl_xor(cs[j], 32, 64);
    }
    __syncthreads();  // (7)
    if (qrt == 0) {
        float* dst = sNagg + w * 128 + c8;
        #pragma unroll
        for (int j = 0; j < 8; ++j) dst[j] = wvalid ? cs[j] : 0.f;
    }
    __syncthreads();
    if (tid < 128) {
        float v = sNagg[tid] + sNagg[128 + tid] + sNagg[256 + tid] + sNagg[384 + tid];
        atomicAdd(&node_agg[(blockIdx.x & 3) * 128 + tid], v);
    }

    // ---- last-block global update ----
    __syncthreads();
    if (tid == 0) {
        __threadfence();
        int old = atomicAdd(done_ctr, 1);
        sLast = (old == (int)gridDim.x - 1);
    }
    __syncthreads();
    if (!sLast) return;

    float* sIn = (float*)smem;        // 384
    float* sP0 = sIn + 384;           // 128
    float* sP1 = sP0 + 128;           // 128
    float* sH = sP1 + 128;            // 128
    float* sG = sH + 128;             // 128
    float* sMR = sG + 128;            // 2
    const int j = tid & 127;
    const int part = tid >> 7;  // 0/1

    if (tid < 128) {
        float v = 0.f;
        #pragma unroll
        for (int c = 0; c < 4; ++c) v += atomicAdd(&node_agg[c * 128 + tid], 0.f);
        #pragma unroll
        for (int c = 0; c < 4; ++c) atomicExch(&node_agg[c * 128 + tid], 0.f);
        sIn[tid] = v;
        sIn[256 + tid] = g[tid];  // previous dispatch's write: coherent
    } else {
        float v = 0.f;
        #pragma unroll
        for (int c = 0; c < 8; ++c) v += edge_agg[c * 128 + j];  // prev dispatch
        #pragma unroll
        for (int c = 0; c < 8; ++c) edge_agg[c * 128 + j] = 0.f;
        sIn[128 + j] = v;
    }
    __syncthreads();
    {
        float p = 0.f;
        for (int k = 0; k < 192; ++k) {
            int kk = part * 192 + k;
            p += sIn[kk] * gW0[(size_t)kk * 128 + j];
        }
        (part ? sP1 : sP0)[j] = p;
    }
    __syncthreads();
    if (tid < 128) sH[tid] = fmaxf(gb0[tid] + sP0[tid] + sP1[tid], 0.f);
    __syncthreads();
    {
        float p = 0.f;
        for (int k = 0; k < 64; ++k) {
            int kk = part * 64 + k;
            p += sH[kk] * gW1[(size_t)kk * 128 + j];
        }
        (part ? sP1 : sP0)[j] = p;
    }
    __syncthreads();
    float res = 0.f;
    if (tid < 128) {
        res = fmaxf(gb1[tid] + sP0[tid] + sP1[tid], 0.f) + sIn[256 + tid];
        sP0[tid] = res;
        sP1[tid] = res * res;
    }
    __syncthreads();
    if (tid < 64) {
        float a = sP0[tid] + sP0[tid + 64];
        float q = sP1[tid] + sP1[tid + 64];
        #pragma unroll
        for (int off = 1; off < 64; off <<= 1) {
            a += __shfl_xor(a, off, 64);
            q += __shfl_xor(q, off, 64);
        }
        if (tid == 0) {
            float m = a * (1.f / 128.f);
            float v = q * (1.f / 128.f) - m * m;
            sMR[0] = m;
            sMR[1] = rsqrtf(v + LN_EPS);
        }
    }
    __syncthreads();
    if (tid < 128) {
        float go = (res - sMR[0]) * sMR[1] * glnS[tid] + glnO[tid];
        g[tid] = go;
        sG[tid] = go;
    }
    __syncthreads();
    if (do_next) {
        float pe = 0.f, pn = 0.f;
        for (int k = 0; k < 64; ++k) {
            int kk = part * 64 + k;
            float gv = sG[kk];
            pe += gv * eW0g[(size_t)kk * 128 + j];
            pn += gv * nW0g[(size_t)kk * 128 + j];
        }
        (part ? sP1 : sP0)[j] = pe;
        sIn[part * 128 + j] = pn;
        __syncthreads();
        if (tid < 128) {
            gve[tid] = eb0n[tid] + sP0[tid] + sP1[tid];
            gvn[tid] = nb0n[tid] + sIn[tid] + sIn[128 + tid];
        }
    }
    if (do_dec && tid < 8) {
        float a = decb[tid];
        for (int k = 0; k < 128; ++k) a += sG[k] * decW[k * 8 + tid];
        out[tid] = a;
    }
}

extern "C" void kernel_launch(void* const* d_in, const int* in_sizes, int n_in, void* d_out,
                              int out_size, void* d_ws, size_t ws_size, hipStream_t stream) {
    (void)in_sizes; (void)n_in; (void)out_size; (void)ws_size;
    const float* nodes = (const float*)d_in[0];
    const float* edges = (const float*)d_in[1];
    const float* globals_ = (const float*)d_in[2];
    const int* senders = (const int*)d_in[3];
    const int* receivers = (const int*)d_in[4];
    const float* emb_node_W = (const float*)d_in[5];
    const float* emb_node_b = (const float*)d_in[6];
    const float* emb_edge_W = (const float*)d_in[7];
    const float* emb_edge_b = (const float*)d_in[8];
    const float* emb_glob_W = (const float*)d_in[9];
    const float* emb_glob_b = (const float*)d_in[10];
    const float* edge_W0 = (const float*)d_in[11];
    const float* edge_b0 = (const float*)d_in[12];
    const float* edge_W1 = (const float*)d_in[13];
    const float* edge_b1 = (const float*)d_in[14];
    const float* node_W0 = (const float*)d_in[15];
    const float* node_b0 = (const float*)d_in[16];
    const float* node_W1 = (const float*)d_in[17];
    const float* node_b1 = (const float*)d_in[18];
    const float* glob_W0 = (const float*)d_in[19];
    const float* glob_b0 = (const float*)d_in[20];
    const float* glob_W1 = (const float*)d_in[21];
    const float* glob_b1 = (const float*)d_in[22];
    const float* ln_scale = (const float*)d_in[23];
    const float* ln_offset = (const float*)d_in[24];
    const float* dec_W = (const float*)d_in[25];
    const float* dec_b = (const float*)d_in[26];

    char* ws = (char*)d_ws;
    size_t off = 0;
    auto alloc = [&](size_t bytes) -> char* {
        char* p = ws + off;
        off += (bytes + 255) & ~(size_t)255;
        return p;
    };
    bf16* e = (bf16*)alloc((size_t)NE * NL * 2);
    bf16* e_new = (bf16*)alloc((size_t)NE * NL * 2);
    float* n = (float*)alloc((size_t)NN * NL * 4);
    bf16* nsW = (bf16*)alloc((size_t)NN * NL * 2);
    bf16* nrW = (bf16*)alloc((size_t)NN * NL * 2);
    bf16* sent = (bf16*)alloc((size_t)NN * NL * 2);
    bf16* recv = (bf16*)alloc((size_t)NN * NL * 2);
    bf16* imgs = (bf16*)alloc((size_t)24 * 16384 * 2);
    float* eagg = (float*)alloc(8 * 128 * 4);
    float* nagg = (float*)alloc(4 * 128 * 4);
    float* g = (float*)alloc(128 * 4);
    float* gve = (float*)alloc(128 * 4);
    float* gvn = (float*)alloc(128 * 4);
    int* done = (int*)alloc(16 * 4);
    int* deg = (int*)alloc((size_t)2 * NN * 4);  // deg_s | deg_r contiguous
    int* deg_s = deg;
    int* deg_r = deg + NN;
    int* rs_s = (int*)alloc((size_t)(NN + 1) * 4);
    int* rs_r = (int*)alloc((size_t)(NN + 1) * 4);
    int* cur_s = (int*)alloc((size_t)NN * 4);
    int* cur_r = (int*)alloc((size_t)NN * 4);
    int* perm = (int*)alloc((size_t)NE * 4);
    int* snd_s = (int*)alloc((size_t)NE * 4);
    int* rcv_s = (int*)alloc((size_t)NE * 4);
    int* csr_r = (int*)alloc((size_t)NE * 4);

    const int NB_N = (NN + 63) / 64;     // 157
    const int NB_E = NE / 128;           // 1250
    const int NB_EMB = NE / 128;         // 1250
    const int NB_SC = (NE + 255) / 256;  // 625
    const int NB_AGG = NN / 4;           // 2500

    auto img = [&](int s, int kind) -> const bf16* {
        return imgs + ((size_t)s * 8 + kind) * 16384;
    };

    k_prep<<<26, 256, 0, stream>>>(edge_W0, edge_W1, node_W0, node_W1, imgs, globals_,
                                   emb_glob_W, emb_glob_b, g, edge_b0, node_b0, gve, gvn,
                                   deg, eagg, nagg, done);

    k_hist<<<NB_SC, 256, 0, stream>>>(senders, receivers, deg_s, deg_r);
    k_scan<<<1, 1024, 0, stream>>>(deg_s, rs_s, cur_s, deg_r, rs_r, cur_r);
    k_scatter_s<<<NB_SC, 256, 0, stream>>>(senders, receivers, cur_s, perm, snd_s, rcv_s);
    k_scatter_r<<<NB_SC, 256, 0, stream>>>(rcv_s, cur_r, csr_r);

    k_embed_nodes<<<NB_N, 256, 0, stream>>>(nodes, emb_node_W, emb_node_b, n, img(0, 1),
                                            img(0, 2), nsW, nrW);
    k_embed_edges<<<NB_EMB, 256, 0, stream>>>(edges, perm, emb_edge_W, emb_edge_b, e);

    for (int s = 0; s < 3; ++s) {
        const int last = (s == 2);
        k_edge<<<NB_E, 512, 0, stream>>>(e, e_new, nsW, nrW, eagg, snd_s, rcv_s, img(s, 0),
                                         img(s, 3), gve, edge_b1 + s * 128,
                                         ln_scale + (s * 3 + 1) * 128,
                                         ln_offset + (s * 3 + 1) * 128);
        k_agg<<<NB_AGG, 256, 0, stream>>>(e_new, rs_s, rs_r, csr_r, sent, recv);
        const float* eW0g = last ? edge_W0 : edge_W0 + (size_t)(s + 1) * 512 * 128 + 384 * 128;
        const float* eb0n = last ? edge_b0 : edge_b0 + (s + 1) * 128;
        const float* nW0g = last ? node_W0 : node_W0 + (size_t)(s + 1) * 512 * 128 + 384 * 128;
        const float* nb0n = last ? node_b0 : node_b0 + (s + 1) * 128;
        k_node<<<NB_N, 256, 0, stream>>>(
            n, sent, recv, nagg, img(s, 4), img(s, 7), gvn, node_b1 + s * 128,
            ln_scale + (s * 3 + 0) * 128, ln_offset + (s * 3 + 0) * 128,
            img(last ? 0 : s + 1, 1), img(last ? 0 : s + 1, 2), nsW, nrW, !last,
            done + s, eagg, g, glob_W0 + (size_t)s * 384 * 128, glob_b0 + s * 128,
            glob_W1 + (size_t)s * 128 * 128, glob_b1 + s * 128, ln_scale + (s * 3 + 2) * 128,
            ln_offset + (s * 3 + 2) * 128, eW0g, eb0n, nW0g, nb0n, gve, gvn, dec_W, dec_b,
            (float*)d_out, !last, last);
    }
}